// Round 6
// baseline (1410.912 us; speedup 1.0000x reference)
//
#include <hip/hip_runtime.h>
#include <hip/hip_bf16.h>

// Problem constants: T=512, B=32, V=4096, S=64, L=2S+1=129
constexpr int T = 512;
constexpr int B = 32;
constexpr int V = 4096;
constexpr int S = 64;
constexpr int GW2 = 68;            // padded gathered width -> 16B-aligned rows
constexpr int CH = 64;             // timesteps per LDS chunk (2*64*68*4 = 34 KB)
constexpr int NCH = T / CH;        // 8 chunks
constexpr int NGBLK = (T * B) / 4; // 4096 gather blocks (4 rows/block)

#define NEG (-1e30f)

__device__ inline float lae2(float a, float b) {
    float m = fmaxf(a, b);
    return m + __logf(__expf(a - m) + __expf(b - m));
}
__device__ inline float lae3(float a, float b, float c) {
    float m = fmaxf(fmaxf(a, b), c);
    return m + __logf(__expf(a - m) + __expf(b - m) + __expf(c - m));
}

// lane 0 polls the chunk counter until `target` rows are published, then the
// whole wave acquire-fences so subsequent g reads see the producers' stores.
__device__ inline void wait_chunk(int* cp, int target) {
    if ((threadIdx.x & 63) == 0) {
        while (__hip_atomic_load(cp, __ATOMIC_RELAXED, __HIP_MEMORY_SCOPE_AGENT) < target)
            __builtin_amdgcn_s_sleep(8);
    }
    __threadfence();   // acquire side
}

// Fused kernel.
//  blocks 0..B-1   : scan role, one block (4 waves) per batch element.
//  blocks B..B+4095: gather role, 4 rows/block, t-major (W = t*32 + b) so
//                    early timesteps complete first across all batches.
// Producers publish per-(b,chunk) row counts with release semantics; the scan
// block's staging waves consume chunks as they become ready, overlapping the
// serial alpha recursion with the bulk of the gather.
__global__ __launch_bounds__(256) void ctc_fused_kernel(
    const float* __restrict__ acts, const int* __restrict__ labels,
    const int* __restrict__ in_len, const int* __restrict__ tgt_len,
    float* __restrict__ g, int* __restrict__ cnt, float* __restrict__ out) {
    __shared__ float sg[2][CH][GW2];
    int tid = threadIdx.x;
    int lane = tid & 63;
    int wave = tid >> 6;

    if (blockIdx.x >= B) {
        // ---------------- gather role: one (t,b) row per wave ----------------
        int W = (blockIdx.x - B) * 4 + wave;   // row id, t-major: W = t*B + b
        int t = W >> 5;                        // / B (B=32)
        int b = W & 31;                        // % B
        int Tl = in_len[b];
        if (t >= Tl) return;                   // row never consumed (alpha frozen)

        const float* row = acts + (size_t)W * V;
        const float4* row4 = reinterpret_cast<const float4*>(row);

        int sym = labels[b * S + lane];
        float4 r[16];
#pragma unroll
        for (int j = 0; j < 16; ++j) r[j] = row4[j * 64 + lane];
        float gv = row[sym];                   // L1-hit gather, hides under trees

        float vmax = -INFINITY;
#pragma unroll
        for (int j = 0; j < 16; ++j)
            vmax = fmaxf(vmax, fmaxf(fmaxf(r[j].x, r[j].y), fmaxf(r[j].z, r[j].w)));
#pragma unroll
        for (int off = 1; off < 64; off <<= 1)
            vmax = fmaxf(vmax, __shfl_xor(vmax, off));

        float acc = 0.f;
#pragma unroll
        for (int j = 0; j < 16; ++j) {
            acc += __expf(r[j].x - vmax) + __expf(r[j].y - vmax) +
                   __expf(r[j].z - vmax) + __expf(r[j].w - vmax);
        }
#pragma unroll
        for (int off = 1; off < 64; off <<= 1)
            acc += __shfl_xor(acc, off);

        float lse = vmax + __logf(acc);

        float* grow = g + (size_t)(b * T + t) * GW2;
        grow[1 + lane] = gv - lse;
        if (lane == 0) grow[0] = r[0].x - lse; // blank: row[0] already in regs

        __threadfence();                       // release: rows visible before count
        if (lane == 0)
            __hip_atomic_fetch_add(&cnt[b * NCH + (t >> 6)], 1,
                                   __ATOMIC_RELAXED, __HIP_MEMORY_SCOPE_AGENT);
        return;
    }

    // ---------------- scan role: batch b = blockIdx.x ----------------
    int b = blockIdx.x;
    const float* gb = g + (size_t)b * T * GW2;
    int* cb = cnt + b * NCH;
    int Tl = in_len[b];                        // in [T/2, T]
    int nch = (Tl + CH - 1) / CH;

    // wait for + stage chunk 0 (all 4 waves)
    {
        int tcnt = min(CH, Tl);
        wait_chunk(cb, tcnt);
        int F4 = tcnt * (GW2 / 4);
        const float4* src = reinterpret_cast<const float4*>(gb);
        float4* dst = reinterpret_cast<float4*>(&sg[0][0][0]);
        for (int i = tid; i < F4; i += 256) dst[i] = src[i];
    }
    __syncthreads();

    float a0 = NEG, a1 = NEG, a2 = NEG;
    bool skip1 = false;
    if (wave == 0) {
        int myLab = labels[b * S + lane];
        skip1 = (lane >= 1) && (myLab != labels[b * S + lane - 1]);
        float lpb0 = sg[0][0][0];
        float lpl0 = sg[0][0][1 + lane];
        a0 = (lane == 0) ? lpb0 : NEG;         // state 0 (blank)
        a1 = (lane == 0) ? lpl0 : NEG;         // state 1 (label 0)
    }

    int t = 1;
    for (int c = 0; c < nch; ++c) {
        int buf = c & 1;
        int tEnd = min((c + 1) * CH, Tl);
        if (wave == 0) {
            int tc = t - c * CH;
            int tcEnd = tEnd - c * CH;
            if (tc < tcEnd) {
                float lpb = sg[buf][tc][0];
                float lpl = sg[buf][tc][1 + lane];
                for (; tc < tcEnd; ++tc) {
                    float nlpb = 0.f, nlpl = 0.f;
                    if (tc + 1 < tcEnd) {      // depth-1 prefetch within chunk
                        nlpb = sg[buf][tc + 1][0];
                        nlpl = sg[buf][tc + 1][1 + lane];
                    }
                    float pa1 = __shfl_up(a1, 1);
                    if (lane == 0) pa1 = NEG;
                    float n0 = lae2(a0, pa1) + lpb;                    // even
                    float n1 = lae3(a1, a0, skip1 ? pa1 : NEG) + lpl;  // odd
                    float n2 = lae2(a2, a1) + lpb;                     // 128
                    a0 = n0; a1 = n1; a2 = n2;
                    lpb = nlpb; lpl = nlpl;
                }
            }
            t = tEnd;
        } else if (c + 1 < nch) {
            // waves 1-3: wait for chunk c+1 readiness, then stage it
            int t0 = (c + 1) * CH;
            int tcnt = min(CH, Tl - t0);
            wait_chunk(cb + c + 1, tcnt);
            int F4 = tcnt * (GW2 / 4);
            const float4* src = reinterpret_cast<const float4*>(gb + (size_t)t0 * GW2);
            float4* dst = reinterpret_cast<float4*>(&sg[buf ^ 1][0][0]);
            for (int i = tid - 64; i < F4; i += 192) dst[i] = src[i];
        }
        __syncthreads();
    }

    if (tid < 64) {
        int tl = tgt_len[b];                   // == S here, handled generally
        float ahi, alo;
        if (tl >= S) {
            ahi = __shfl(a2, 63);              // state 2S = 128
            alo = __shfl(a1, S - 1);           // state 2S-1 = 127
        } else if (tl >= 1) {
            ahi = __shfl(a0, tl);
            alo = __shfl(a1, tl - 1);
        } else {
            ahi = __shfl(a0, 0);
            alo = ahi;
        }
        if (lane == 0) {
            float m = fmaxf(ahi, alo);
            float nll = -(m + __logf(__expf(ahi - m) + __expf(alo - m)));
            if (!(nll < 1e29f)) nll = 0.f;
            atomicAdd(out, nll);
        }
    }
}

extern "C" void kernel_launch(void* const* d_in, const int* in_sizes, int n_in,
                              void* d_out, int out_size, void* d_ws, size_t ws_size,
                              hipStream_t stream) {
    const float* acts = (const float*)d_in[0];
    const int* labels = (const int*)d_in[1];
    const int* in_len = (const int*)d_in[2];
    const int* tgt_len = (const int*)d_in[3];
    float* out = (float*)d_out;

    float* g = (float*)d_ws;                       // B*T*GW2 floats = 4.46 MB
    int* cnt = (int*)((char*)d_ws + (8 << 20));    // chunk counters at +8 MB

    hipMemsetAsync(out, 0, sizeof(float), stream);
    hipMemsetAsync(cnt, 0, B * NCH * sizeof(int), stream);

    ctc_fused_kernel<<<B + NGBLK, 256, 0, stream>>>(acts, labels, in_len,
                                                    tgt_len, g, cnt, out);
}

// Round 8
// 403.197 us; speedup vs baseline: 3.4993x; 3.4993x over previous
//
#include <hip/hip_runtime.h>
#include <hip/hip_bf16.h>

// Problem constants: T=512, B=32, V=4096, S=64, L=2S+1=129
constexpr int T = 512;
constexpr int B = 32;
constexpr int V = 4096;
constexpr int S = 64;
constexpr int GW2 = 68;    // padded gathered width -> 16B-aligned rows
constexpr int CH = 119;    // timesteps per LDS chunk: (2*119+1)*68*4 = 65008 B <= 64 KB

#define NEG (-1e30f)
#define LOG2E 1.44269504f
#define LN2 0.69314718f

// native base-2 exp/log: single v_exp_f32 / v_log_f32 (ISA is base-2 native)
__device__ inline float fexp2(float x) { return __builtin_amdgcn_exp2f(x); }
__device__ inline float flog2(float x) { return __builtin_amdgcn_logf(x); }

// log-domain adds in BASE 2
__device__ inline float lae2(float a, float b) {
    float m = fmaxf(a, b);
    return m + flog2(fexp2(a - m) + fexp2(b - m));
}
__device__ inline float lae3(float a, float b, float c) {
    float m = fmaxf(fmaxf(a, b), c);
    return m + flog2(fexp2(a - m) + fexp2(b - m) + fexp2(c - m));
}

// lane i <- lane i-1, lane 0 <- fill. DPP wave_shr1 (0x138): pure VALU,
// no LDS round-trip; invalid lane keeps `old` operand (= fill).
__device__ inline float wave_shr1(float x, float fill) {
    int r = __builtin_amdgcn_update_dpp(__float_as_int(fill), __float_as_int(x),
                                        0x138, 0xf, 0xf, false);
    return __int_as_float(r);
}

// Kernel 1: one row (t,b) per WAVE, 4 waves/block. Row held in 16 float4
// regs; max/sum reductions are pure shfl_xor. Rows with t >= input_length[b]
// are never consumed by the scan (alpha frozen) -> skip entirely (~25% of
// the 256 MB acts read). Output g is in LOG2 domain.
__global__ __launch_bounds__(256) void lse_gather_kernel(
    const float* __restrict__ acts, const int* __restrict__ labels,
    const int* __restrict__ in_len, float* __restrict__ g) {
    int w = blockIdx.x * 4 + (threadIdx.x >> 6);   // row id tb = t*B + b
    int lane = threadIdx.x & 63;
    int t = w >> 5;               // / B (B=32)
    int b = w & 31;               // % B
    if (t >= in_len[b]) return;   // never consumed

    const float* row = acts + (size_t)w * V;
    const float4* row4 = reinterpret_cast<const float4*>(row);

    int sym = labels[b * S + lane];   // independent early load
    float4 r[16];
#pragma unroll
    for (int j = 0; j < 16; ++j) r[j] = row4[j * 64 + lane];
    float gv = row[sym];              // L1-hit gather; hides under trees

    float vmax = -INFINITY;
#pragma unroll
    for (int j = 0; j < 16; ++j)
        vmax = fmaxf(vmax, fmaxf(fmaxf(r[j].x, r[j].y), fmaxf(r[j].z, r[j].w)));
#pragma unroll
    for (int off = 1; off < 64; off <<= 1)
        vmax = fmaxf(vmax, __shfl_xor(vmax, off));

    float acc = 0.f;
#pragma unroll
    for (int j = 0; j < 16; ++j) {
        acc += __expf(r[j].x - vmax) + __expf(r[j].y - vmax) +
               __expf(r[j].z - vmax) + __expf(r[j].w - vmax);
    }
#pragma unroll
    for (int off = 1; off < 64; off <<= 1)
        acc += __shfl_xor(acc, off);

    float lse = vmax + __logf(acc);   // ln domain

    float* grow = g + (size_t)(b * T + t) * GW2;
    grow[1 + lane] = (gv - lse) * LOG2E;              // -> log2 domain
    if (lane == 0) grow[0] = (r[0].x - lse) * LOG2E;  // blank from regs
}

// Kernel 2: CTC forward recursion, one 256-thread block (4 waves) per batch.
// Wave 0 scans from LDS (base-2 math, DPP shift, branch-free depth-1
// prefetch); waves 1-3 double-buffer-stage the next chunk. Lane i of wave 0
// holds extended states 2i (a0), 2i+1 (a1); lane 63 also holds state 128 (a2).
__global__ __launch_bounds__(256) void ctc_fwd_kernel(
    const float* __restrict__ g, const int* __restrict__ labels,
    const int* __restrict__ in_len, const int* __restrict__ tgt_len,
    float* __restrict__ out) {
    __shared__ float sg[2 * CH + 1][GW2];   // +1 row: OOB-safe prefetch pad
    int b = blockIdx.x;
    int tid = threadIdx.x;
    int lane = tid & 63;
    int wave = tid >> 6;
    const float* gb = g + (size_t)b * T * GW2;
    int Tl = in_len[b];                       // in [T/2, T]
    int nch = (Tl + CH - 1) / CH;

    // stage chunk 0 with all 4 waves
    {
        int tcnt = min(CH, Tl);
        int F4 = tcnt * (GW2 / 4);
        const float4* src = reinterpret_cast<const float4*>(gb);
        float4* dst = reinterpret_cast<float4*>(&sg[0][0]);
        for (int i = tid; i < F4; i += 256) dst[i] = src[i];
    }
    __syncthreads();

    float a0 = NEG, a1 = NEG, a2 = NEG;
    bool skip1 = false;
    if (wave == 0) {
        int myLab = labels[b * S + lane];
        skip1 = (lane >= 1) && (myLab != labels[b * S + lane - 1]);
        float lpb0 = sg[0][0];
        float lpl0 = sg[0][1 + lane];
        a0 = (lane == 0) ? lpb0 : NEG;        // state 0 (blank)
        a1 = (lane == 0) ? lpl0 : NEG;        // state 1 (label 0)
    }

    int t = 1;
    for (int c = 0; c < nch; ++c) {
        int buf = c & 1;
        int base = buf * CH;
        int tEnd = min((c + 1) * CH, Tl);
        if (wave == 0) {
            int tc = t - c * CH;
            int tcEnd = tEnd - c * CH;
            if (tc < tcEnd) {
                float lpb = sg[base + tc][0];
                float lpl = sg[base + tc][1 + lane];
                for (; tc < tcEnd; ++tc) {
                    // branch-free depth-1 prefetch (pad row makes tc+1 safe;
                    // garbage at chunk end is discarded at next chunk start)
                    float nlpb = sg[base + tc + 1][0];
                    float nlpl = sg[base + tc + 1][1 + lane];
                    float pa1 = wave_shr1(a1, NEG);      // lane0 -> NEG via DPP old
                    float pa1s = skip1 ? pa1 : NEG;
                    float n0 = lae2(a0, pa1) + lpb;                 // even state
                    float n1 = lae3(a1, a0, pa1s) + lpl;            // odd state
                    float n2 = lae2(a2, a1) + lpb;                  // state 128
                    a0 = n0; a1 = n1; a2 = n2;
                    lpb = nlpb; lpl = nlpl;
                }
            }
            t = tEnd;
        } else {
            // waves 1-3: stage chunk c+1 into the other buffer
            int t0 = (c + 1) * CH;
            if (t0 < Tl) {
                int tcnt = min(CH, Tl - t0);
                int F4 = tcnt * (GW2 / 4);
                const float4* src = reinterpret_cast<const float4*>(gb + (size_t)t0 * GW2);
                float4* dst = reinterpret_cast<float4*>(&sg[(base ^ CH)][0]);
                for (int i = tid - 64; i < F4; i += 192) dst[i] = src[i];
            }
        }
        __syncthreads();
    }

    if (tid < 64) {
        int tl = tgt_len[b];                  // == S here, handled generally
        float ahi, alo;
        if (tl >= S) {
            ahi = __shfl(a2, 63);             // state 2S = 128
            alo = __shfl(a1, S - 1);          // state 2S-1 = 127
        } else if (tl >= 1) {
            ahi = __shfl(a0, tl);
            alo = __shfl(a1, tl - 1);
        } else {
            ahi = __shfl(a0, 0);
            alo = ahi;
        }
        if (lane == 0) {
            float nll = -(lae2(ahi, alo) * LN2);   // log2 -> ln
            if (!(nll < 1e29f)) nll = 0.f;
            atomicAdd(out, nll);
        }
    }
}

extern "C" void kernel_launch(void* const* d_in, const int* in_sizes, int n_in,
                              void* d_out, int out_size, void* d_ws, size_t ws_size,
                              hipStream_t stream) {
    const float* acts = (const float*)d_in[0];
    const int* labels = (const int*)d_in[1];
    const int* in_len = (const int*)d_in[2];
    const int* tgt_len = (const int*)d_in[3];
    float* out = (float*)d_out;
    float* g = (float*)d_ws;   // B*T*GW2 floats = 4.46 MB

    (void)hipMemsetAsync(out, 0, sizeof(float), stream);

    lse_gather_kernel<<<(T * B) / 4, 256, 0, stream>>>(acts, labels, in_len, g);
    ctc_fwd_kernel<<<B, 256, 0, stream>>>(g, labels, in_len, tgt_len, out);
}